// Round 3
// baseline (216.226 us; speedup 1.0000x reference)
//
#include <hip/hip_runtime.h>

// Haar 3-level DWT, fully fused, one float4 per thread.
// x: [B=2048, L=16384] fp32
// out: concat(cA3[B,2048], cD3[B,2048], cD2[B,4096], cD1[B,8192]) fp32
//
// Thread u owns x[4u..4u+3] (one perfectly-coalesced 16B load):
//   level1: 2 (a,d) pairs -> cD1 float2 store (full lanes)
//   level2: 1 (a,d) pair  -> cD2 float2 store (even lanes, paired via shuffle)
//   level3: exchange a2 with lane^1; even lanes compute cA3, odd lanes cD3,
//           single full-lane scalar store (two 128B segments per wave)
// All loads/stores non-temporal (stream-once data).

#define HS 0.7071067811865476f

typedef float vf4 __attribute__((ext_vector_type(4)));
typedef float vf2 __attribute__((ext_vector_type(2)));

constexpr int B = 2048;
constexpr int L = 16384;
constexpr int UNITS = B * (L / 4);            // 8,388,608 float4 units
constexpr size_t OFF_CD3 = (size_t)B * 2048;  //  4,194,304
constexpr size_t OFF_CD2 = OFF_CD3 * 2;       //  8,388,608
constexpr size_t OFF_CD1 = OFF_CD2 + (size_t)B * 4096; // 16,777,216

__global__ __launch_bounds__(256) void haar3_kernel(const vf4* __restrict__ x4,
                                                    float* __restrict__ out) {
    const int u = blockIdx.x * 256 + threadIdx.x;   // float4 index, = row*4096 + pos
    const int pos = u & 4095;                        // parity == lane parity

    const vf4 v = __builtin_nontemporal_load(&x4[u]);

    // level 1
    const float a10 = HS * (v.x + v.y), d10 = HS * (v.x - v.y);
    const float a11 = HS * (v.z + v.w), d11 = HS * (v.z - v.w);
    // level 2
    const float a2 = HS * (a10 + a11), d2 = HS * (a10 - a11);

    // cD1: float2 index u (8B/lane, full lanes)
    vf2 d1v; d1v.x = d10; d1v.y = d11;
    __builtin_nontemporal_store(d1v, ((vf2*)(out + OFF_CD1)) + u);

    // exchange with partner lane (pos^1)
    const float a2p = __shfl_xor(a2, 1);
    const float d2p = __shfl_xor(d2, 1);
    const bool even = (pos & 1) == 0;

    // cD2: even lanes store (d2, d2_partner) as float2 at elem OFF_CD2 + u
    if (even) {
        vf2 d2v; d2v.x = d2; d2v.y = d2p;
        __builtin_nontemporal_store(d2v, (vf2*)(out + OFF_CD2 + u));
    }

    // level 3: even lane -> cA3, odd lane -> cD3, same rp3 = u>>1 per pair
    const float v3 = even ? HS * (a2 + a2p) : HS * (a2p - a2);
    const size_t addr3 = (even ? (size_t)0 : OFF_CD3) + (size_t)(u >> 1);
    __builtin_nontemporal_store(v3, out + addr3);
}

extern "C" void kernel_launch(void* const* d_in, const int* in_sizes, int n_in,
                              void* d_out, int out_size, void* d_ws, size_t ws_size,
                              hipStream_t stream) {
    const vf4* x4 = (const vf4*)d_in[0];
    float* out = (float*)d_out;
    constexpr int block = 256;
    constexpr int grid = UNITS / block;             // 32768 blocks
    haar3_kernel<<<grid, block, 0, stream>>>(x4, out);
}